// Round 4
// baseline (262.101 us; speedup 1.0000x reference)
//
#include <hip/hip_runtime.h>
#include <hip/hip_bf16.h>
#include <cstdint>
#include <cstddef>

// Problem constants (fixed by reference)
#define BB 4
#define NN 4096
#define NROW (BB*NN)          // 16384 rows
#define SEGW 32               // slots per (row, m-split) segment
#define NSEG 8                // m-splits
#define SROW (SEGW*NSEG)      // 256 survivor slots per row
#define QPf 27.7f             // push threshold on w_approx (27 + margin)
#define STRICT_KEY (49152u<<12)  // key bound for w_approx < 27.0  ((27+69)*512)
#define DQ 386u               // selection window in q units (>> 2*eps*512)

typedef float v2f   __attribute__((ext_vector_type(2)));
typedef float f32x16 __attribute__((ext_vector_type(16)));
typedef short s16x8 __attribute__((ext_vector_type(8)));
typedef __bf16 bf16x8 __attribute__((ext_vector_type(8)));

__device__ __forceinline__ v2f pkfma(v2f a, v2f b, v2f c) {
  return __builtin_elementwise_fma(a, b, c);
}
__device__ __forceinline__ unsigned short f2bf(float f) {
  unsigned u = __float_as_uint(f);
  u += 0x7FFFu + ((u >> 16) & 1u);      // RNE (no NaN/Inf in data)
  return (unsigned short)(u >> 16);
}
__device__ __forceinline__ float bf2f(unsigned short h) {
  return __uint_as_float(((unsigned)h) << 16);
}

// ---------------------------------------------------------------------------
// K1: prep. xT f32 [point][c]; xh/xl bf16 hi/lo split; xxf/xxd norms;
//     uT = W1.x, vT = (W2-W1).x  [point][o]  (weights in registers)
// ---------------------------------------------------------------------------
__global__ __launch_bounds__(256) void k1_prep(
    const float* __restrict__ x, const float* __restrict__ W,
    float* __restrict__ xT, unsigned short* __restrict__ xh, unsigned short* __restrict__ xl,
    float* __restrict__ xxf, double* __restrict__ xxd,
    float* __restrict__ uT, float* __restrict__ vT)
{
  __shared__ float xc[64][65];   // [c][n]
  __shared__ float xr[64][68];   // [n][c]
  __shared__ float w1[64][65];
  __shared__ float wd[64][65];
  int t = threadIdx.x;
  int b  = blockIdx.x >> 6;
  int n0 = (blockIdx.x & 63) * 64;

  for (int i = t; i < 4096; i += 256) {
    int o = i >> 6, c = i & 63;
    float a = W[o*128 + c];
    w1[o][c] = a;
    wd[o][c] = W[o*128 + 64 + c] - a;
  }
  for (int i = t; i < 4096; i += 256) {
    int c = i >> 6, n = i & 63;
    xc[c][n] = x[((size_t)b*64 + c)*4096 + n0 + n];
  }
  __syncthreads();

  for (int i = t; i < 4096; i += 256) {
    int n = i >> 6, c = i & 63;
    float v = xc[c][n];
    xr[n][c] = v;
    size_t pi = ((size_t)b*4096 + n0 + n)*64 + c;
    xT[pi] = v;
    unsigned short h = f2bf(v);
    float l = v - bf2f(h);
    xh[pi] = h;
    xl[pi] = f2bf(l);
  }
  if (t < 64) {
    int n = t;
    float s0=0,s1=0,s2=0,s3=0; double sd=0.0;
    for (int c = 0; c < 64; c += 4) {
      float a0=xc[c][n],a1=xc[c+1][n],a2=xc[c+2][n],a3=xc[c+3][n];
      s0=fmaf(a0,a0,s0); s1=fmaf(a1,a1,s1); s2=fmaf(a2,a2,s2); s3=fmaf(a3,a3,s3);
      sd += (double)a0*a0 + (double)a1*a1 + (double)a2*a2 + (double)a3*a3;
    }
    xxf[(size_t)b*4096 + n0 + n] = (s0+s1)+(s2+s3);
    xxd[(size_t)b*4096 + n0 + n] = sd;
  }
  v2f w1r[32], wdr[32];
  int o = t & 63;
  #pragma unroll
  for (int j = 0; j < 32; ++j) {
    w1r[j].x = w1[o][2*j]; w1r[j].y = w1[o][2*j+1];
    wdr[j].x = wd[o][2*j]; wdr[j].y = wd[o][2*j+1];
  }
  __syncthreads();

  for (int i = t; i < 4096; i += 256) {
    int n = i >> 6;
    v2f au; au.x=0.f; au.y=0.f;
    v2f av; av.x=0.f; av.y=0.f;
    #pragma unroll
    for (int cb = 0; cb < 16; ++cb) {
      float4 xv = *(const float4*)&xr[n][cb*4];
      v2f p0; p0.x = xv.x; p0.y = xv.y;
      v2f p1; p1.x = xv.z; p1.y = xv.w;
      au = pkfma(w1r[2*cb],   p0, au);
      au = pkfma(w1r[2*cb+1], p1, au);
      av = pkfma(wdr[2*cb],   p0, av);
      av = pkfma(wdr[2*cb+1], p1, av);
    }
    size_t idx = ((size_t)b*4096 + n0 + n)*64 + o;
    uT[idx] = au.x + au.y;
    vT[idx] = av.x + av.y;
  }
}

// ---------------------------------------------------------------------------
// K2: split-bf16 MFMA Gram screen, register-ballot push (no atomics at all).
// Grid = 64 n-blocks x 8 m-splits. Per-row slot counters live in a VGPR on
// owner lane = local row; takers read base via v_readlane (wave-uniform),
// position via ballot prefix-popcount; stores are fire-and-forget.
// ---------------------------------------------------------------------------
__global__ __launch_bounds__(256) void k2_screen(
    const unsigned short* __restrict__ xh, const unsigned short* __restrict__ xl,
    const float* __restrict__ xxf,
    unsigned* __restrict__ counts, unsigned* __restrict__ surv)
{
  __shared__ unsigned short mh[2][8192];   // [buf][128 m][64 c], XOR-swizzled
  __shared__ unsigned short ml[2][8192];
  int t  = threadIdx.x;
  int nb = blockIdx.x >> 3;
  int ms = blockIdx.x & 7;
  int row0 = nb * 256;
  int b = row0 >> 12;
  int mbase = ms * 512;
  const unsigned short* xhB = xh + ((size_t)b*4096)*64;
  const unsigned short* xlB = xl + ((size_t)b*4096)*64;

  int wv = t >> 6, lane = t & 63;
  int lr = lane & 31, oct = lane >> 5;
  unsigned long long belowoct = ((lane == 63) ? 0x7FFFFFFFFFFFFFFFull
                                              : ((1ull << lane) - 1ull))
                              & (oct ? 0xFFFFFFFF00000000ull : 0x00000000FFFFFFFFull);
  int cnt = 0;   // slot counter for my owned local row (= lane) of this wave

  // A-fragments in registers (A,B fed with identical lane->element maps)
  s16x8 ah[2][4], al[2][4];
  #pragma unroll
  for (int nt = 0; nt < 2; ++nt)
    #pragma unroll
    for (int ks = 0; ks < 4; ++ks) {
      size_t rbase = ((size_t)(row0 + wv*64 + nt*32 + lr))*64 + ks*16 + oct*8;
      ah[nt][ks] = *(const s16x8*)(xh + rbase);
      al[nt][ks] = *(const s16x8*)(xl + rbase);
    }

  // stage chunk 0 (LDS write swizzled: byte ^= ((m&7)<<4))
  {
    const char* sH = (const char*)(xhB + (size_t)mbase*64);
    const char* sL = (const char*)(xlB + (size_t)mbase*64);
    #pragma unroll
    for (int it = 0; it < 4; ++it) {
      int j  = it*4096 + t*16;
      int js = j ^ (((j >> 7) & 7) << 4);
      *(float4*)((char*)&mh[0][0] + js) = *(const float4*)(sH + j);
      *(float4*)((char*)&ml[0][0] + js) = *(const float4*)(sL + j);
    }
  }
  __syncthreads();

  for (int ch = 0; ch < 4; ++ch) {
    int cur = ch & 1;
    float4 pH[4], pL[4];
    if (ch < 3) {
      const char* sH = (const char*)(xhB + (size_t)(mbase + (ch+1)*128)*64);
      const char* sL = (const char*)(xlB + (size_t)(mbase + (ch+1)*128)*64);
      #pragma unroll
      for (int it = 0; it < 4; ++it) {
        int j = it*4096 + t*16;
        pH[it] = *(const float4*)(sH + j);
        pL[it] = *(const float4*)(sL + j);
      }
    }
    #pragma unroll
    for (int msub = 0; msub < 4; ++msub) {
      s16x8 bhf[4], blf[4];
      int mloc = msub*32 + lr;
      #pragma unroll
      for (int ks = 0; ks < 4; ++ks) {
        int off  = mloc*128 + ks*32 + oct*16;
        int offs = off ^ ((mloc & 7) << 4);
        bhf[ks] = *(const s16x8*)((const char*)&mh[cur][0] + offs);
        blf[ks] = *(const s16x8*)((const char*)&ml[cur][0] + offs);
      }
      f32x16 a0, a1;
      #pragma unroll
      for (int i = 0; i < 16; ++i) { a0[i] = 0.f; a1[i] = 0.f; }
      #pragma unroll
      for (int ks = 0; ks < 4; ++ks) {
        bf16x8 AH0 = __builtin_bit_cast(bf16x8, ah[0][ks]);
        bf16x8 AH1 = __builtin_bit_cast(bf16x8, ah[1][ks]);
        bf16x8 AL0 = __builtin_bit_cast(bf16x8, al[0][ks]);
        bf16x8 AL1 = __builtin_bit_cast(bf16x8, al[1][ks]);
        bf16x8 BH  = __builtin_bit_cast(bf16x8, bhf[ks]);
        bf16x8 BL  = __builtin_bit_cast(bf16x8, blf[ks]);
        a0 = __builtin_amdgcn_mfma_f32_32x32x16_bf16(AH0, BH, a0, 0, 0, 0);
        a1 = __builtin_amdgcn_mfma_f32_32x32x16_bf16(AH1, BH, a1, 0, 0, 0);
        a0 = __builtin_amdgcn_mfma_f32_32x32x16_bf16(AH0, BL, a0, 0, 0, 0);
        a1 = __builtin_amdgcn_mfma_f32_32x32x16_bf16(AH1, BL, a1, 0, 0, 0);
        a0 = __builtin_amdgcn_mfma_f32_32x32x16_bf16(AL0, BH, a0, 0, 0, 0);
        a1 = __builtin_amdgcn_mfma_f32_32x32x16_bf16(AL1, BH, a1, 0, 0, 0);
      }
      // epilogue: w = xx_m - 2*S ; register-ballot push, no atomics
      int mg = mbase + ch*128 + msub*32 + lr;
      float xxm = xxf[b*4096 + mg];
      #pragma unroll
      for (int i = 0; i < 16; ++i) {
        const int base_i = (i & 3) + 8*(i >> 2);   // C/D row map (measured)
        {
          float w = fmaf(-2.0f, a0[i], xxm);
          bool tk = (w < QPf);
          unsigned long long mk = __ballot(tk);
          unsigned nlo = (unsigned)__popcll(mk & 0x00000000FFFFFFFFull);
          unsigned nhi = (unsigned)__popcll(mk >> 32);
          unsigned clo = (unsigned)__builtin_amdgcn_readlane(cnt, base_i);
          unsigned chi = (unsigned)__builtin_amdgcn_readlane(cnt, base_i + 4);
          unsigned slot = (oct ? chi : clo) + (unsigned)__popcll(mk & belowoct);
          if (tk && slot < SEGW) {
            int qi = (int)((w + 69.0f) * 512.0f);
            qi = min(max(qi, 0), 65535);
            unsigned keyv = ((unsigned)qi << 12) | (unsigned)mg;
            int grow = row0 + wv*64 + base_i + 4*oct;
            surv[(size_t)grow*SROW + ms*SEGW + slot] = keyv;
          }
          cnt += (lane == base_i) ? (int)nlo : ((lane == base_i + 4) ? (int)nhi : 0);
        }
        {
          float w = fmaf(-2.0f, a1[i], xxm);
          bool tk = (w < QPf);
          unsigned long long mk = __ballot(tk);
          unsigned nlo = (unsigned)__popcll(mk & 0x00000000FFFFFFFFull);
          unsigned nhi = (unsigned)__popcll(mk >> 32);
          unsigned clo = (unsigned)__builtin_amdgcn_readlane(cnt, 32 + base_i);
          unsigned chi = (unsigned)__builtin_amdgcn_readlane(cnt, 36 + base_i);
          unsigned slot = (oct ? chi : clo) + (unsigned)__popcll(mk & belowoct);
          if (tk && slot < SEGW) {
            int qi = (int)((w + 69.0f) * 512.0f);
            qi = min(max(qi, 0), 65535);
            unsigned keyv = ((unsigned)qi << 12) | (unsigned)mg;
            int grow = row0 + wv*64 + 32 + base_i + 4*oct;
            surv[(size_t)grow*SROW + ms*SEGW + slot] = keyv;
          }
          cnt += (lane == 32 + base_i) ? (int)nlo : ((lane == 36 + base_i) ? (int)nhi : 0);
        }
      }
    }
    if (ch < 3) {
      __syncthreads();
      int nxt = cur ^ 1;
      #pragma unroll
      for (int it = 0; it < 4; ++it) {
        int j  = it*4096 + t*16;
        int js = j ^ (((j >> 7) & 7) << 4);
        *(float4*)((char*)&mh[nxt][0] + js) = pH[it];
        *(float4*)((char*)&ml[nxt][0] + js) = pL[it];
      }
      __syncthreads();
    }
  }
  // flush per-row counts (owner lane = local row; unique writer)
  counts[(size_t)(row0 + wv*64 + lane)*NSEG + ms] = (unsigned)cnt;
}

// ---------------------------------------------------------------------------
// K3: per-row wave. 8 segments of 32 slots -> 4 key regs (segment pair per
// lane-half); strict check; 16-iter q-bisection; window select (superset of
// true top-20); f64 rescore; bitonic sort; gather/max epilogue.
// ---------------------------------------------------------------------------
__global__ __launch_bounds__(256) void k3_select(
    const float* __restrict__ xT, const double* __restrict__ xxd,
    const unsigned* __restrict__ counts, const unsigned* __restrict__ surv,
    const float* __restrict__ uT, const float* __restrict__ vT,
    float* __restrict__ stage, double* __restrict__ pS1, double* __restrict__ pS2,
    unsigned* __restrict__ slowcnt, unsigned* __restrict__ slowlist)
{
  __shared__ unsigned candm[4][64];
  __shared__ double ps1[4][64], ps2[4][64];
  int wv = threadIdx.x >> 6, lane = threadIdx.x & 63;
  int row = blockIdx.x * 4 + wv;
  int b = row >> 12, n = row & 4095;

  double s1t = 0.0, s2t = 0.0;

  uint4 c0 = *(const uint4*)&counts[(size_t)row*NSEG];
  uint4 c1 = *(const uint4*)&counts[(size_t)row*NSEG + 4];
  bool slow = (c0.x > SEGW) | (c0.y > SEGW) | (c0.z > SEGW) | (c0.w > SEGW)
            | (c1.x > SEGW) | (c1.y > SEGW) | (c1.z > SEGW) | (c1.w > SEGW);

  int half = lane >> 5, idx = lane & 31;
  unsigned sc[4];
  sc[0] = half ? c0.y : c0.x;
  sc[1] = half ? c0.w : c0.z;
  sc[2] = half ? c1.y : c1.x;
  sc[3] = half ? c1.w : c1.z;

  unsigned key[4];
  #pragma unroll
  for (int s = 0; s < 4; ++s) {
    int sg = 2*s + half;
    key[s] = (!slow && idx < (int)sc[s])
           ? surv[(size_t)row*SROW + sg*SEGW + idx] : 0xFFFFFFFFu;
  }

  int strictc = 0;
  #pragma unroll
  for (int s = 0; s < 4; ++s)
    strictc += __popcll(__ballot(key[s] < STRICT_KEY));
  slow = slow || (strictc < 20);

  int sel = 0;
  if (!slow) {
    // bisect on 16-bit q field: find q20 (q of 20th-smallest key)
    unsigned lo = 0u, hi = 1u << 16;
    for (int it = 0; it < 16; ++it) {
      unsigned mid = (lo + hi) >> 1;
      unsigned Tm = mid << 12;
      int c = 0;
      #pragma unroll
      for (int s = 0; s < 4; ++s)
        c += __popcll(__ballot(key[s] < Tm));
      if (c >= 20) hi = mid; else lo = mid;
    }
    unsigned T = (lo + DQ) << 12;    // window covers q20 + DQ - 1
    int c = 0;
    #pragma unroll
    for (int s = 0; s < 4; ++s)
      c += __popcll(__ballot(key[s] < T));
    sel = c;
    if (sel > 64) {
      slow = true;
    } else {
      int base = 0;
      #pragma unroll
      for (int s = 0; s < 4; ++s) {
        unsigned long long mask = __ballot(key[s] < T);
        if (key[s] < T) {
          int pos = base + __popcll(mask & ((1ull << lane) - 1ull));
          candm[wv][pos] = key[s] & 0xFFFu;
        }
        base += __popcll(mask);
      }
    }
  }

  if (!slow) {
    __builtin_amdgcn_wave_barrier();
    unsigned long long k64 = ~0ull;
    if (lane < sel) {
      int m = (int)candm[wv][lane];
      const float* pn = xT + ((size_t)b*4096 + n)*64;
      const float* pm = xT + ((size_t)b*4096 + m)*64;
      double acc = 0.0;
      #pragma unroll 4
      for (int c2 = 0; c2 < 64; c2 += 4) {
        float4 a  = *(const float4*)(pn + c2);
        float4 bf = *(const float4*)(pm + c2);
        acc = fma((double)a.x, (double)bf.x, acc);
        acc = fma((double)a.y, (double)bf.y, acc);
        acc = fma((double)a.z, (double)bf.z, acc);
        acc = fma((double)a.w, (double)bf.w, acc);
      }
      double d = xxd[(size_t)b*4096 + n] + xxd[(size_t)b*4096 + m] - 2.0*acc;
      d = fmax(d, 0.0);
      k64 = (((unsigned long long)__double_as_longlong(d)) & ~0xFFFull)
          | (unsigned long long)m;            // tie -> lower index (lax.top_k)
    }
    #pragma unroll
    for (int kk = 2; kk <= 64; kk <<= 1) {
      #pragma unroll
      for (int j = kk >> 1; j > 0; j >>= 1) {
        unsigned long long o = __shfl_xor(k64, j);
        bool up    = ((lane & kk) == 0);
        bool lower = ((lane & j) == 0);
        unsigned long long mn = (k64 < o) ? k64 : o;
        unsigned long long mx = (k64 < o) ? o : k64;
        k64 = (lower == up) ? mn : mx;
      }
    }
    int mlow = (int)(k64 & 0xFFFull);          // lanes 0..19 = top-20
    const float* ub = uT + (size_t)b*4096*64;
    float mx = -3.4e38f, s1 = 0.f, s2 = 0.f;
    #pragma unroll
    for (int k = 0; k < 20; ++k) {
      int m = __shfl(mlow, k);
      float g = ub[(size_t)m*64 + lane];
      mx = fmaxf(mx, g); s1 += g; s2 = fmaf(g, g, s2);
    }
    size_t ro = ((size_t)b*4096 + n)*64 + lane;
    float v = vT[ro];
    stage[ro] = mx + v;
    double dv = (double)v;
    s1t = (double)s1 + 20.0*dv;
    s2t = (double)s2 + 2.0*dv*(double)s1 + 20.0*dv*dv;
  } else {
    if (lane == 0) { unsigned i = atomicAdd(slowcnt, 1u); slowlist[i] = row; }
  }

  ps1[wv][lane] = s1t; ps2[wv][lane] = s2t;
  __syncthreads();
  if (wv == 0) {
    pS1[(size_t)blockIdx.x*64 + lane] = ps1[0][lane]+ps1[1][lane]+ps1[2][lane]+ps1[3][lane];
    pS2[(size_t)blockIdx.x*64 + lane] = ps2[0][lane]+ps2[1][lane]+ps2[2][lane]+ps2[3][lane];
  }
}

// ---------------------------------------------------------------------------
// K3b: slow path (expected ~15 rows): full f64 scan + 20x extraction.
// ---------------------------------------------------------------------------
__global__ __launch_bounds__(256) void k3b_slow(
    const float* __restrict__ xT, const double* __restrict__ xxd,
    const unsigned* __restrict__ slowcnt, const unsigned* __restrict__ slowlist,
    const float* __restrict__ uT, const float* __restrict__ vT,
    float* __restrict__ stage, double* __restrict__ k3bS1, double* __restrict__ k3bS2)
{
  __shared__ unsigned long long keyl[4096];
  __shared__ unsigned long long red[4];
  __shared__ unsigned t20[20];
  unsigned nslow = *slowcnt;
  int t = threadIdx.x;
  for (unsigned ii = blockIdx.x; ii < nslow; ii += gridDim.x) {
    int row = (int)slowlist[ii];
    int b = row >> 12, n = row & 4095;
    const float* pn = xT + ((size_t)b*4096 + n)*64;
    double xxn = xxd[(size_t)b*4096 + n];
    for (int m = t; m < 4096; m += 256) {
      const float* pm = xT + ((size_t)b*4096 + m)*64;
      double acc = 0.0;
      #pragma unroll 4
      for (int c = 0; c < 64; c += 4) {
        float4 a  = *(const float4*)(pn + c);
        float4 bf = *(const float4*)(pm + c);
        acc = fma((double)a.x, (double)bf.x, acc);
        acc = fma((double)a.y, (double)bf.y, acc);
        acc = fma((double)a.z, (double)bf.z, acc);
        acc = fma((double)a.w, (double)bf.w, acc);
      }
      double d = fmax(xxn + xxd[(size_t)b*4096 + m] - 2.0*acc, 0.0);
      keyl[m] = (((unsigned long long)__double_as_longlong(d)) & ~0xFFFull)
              | (unsigned long long)m;
    }
    __syncthreads();
    for (int k = 0; k < 20; ++k) {
      unsigned long long mn = ~0ull;
      #pragma unroll
      for (int s = 0; s < 16; ++s) {
        unsigned long long v = keyl[t + s*256];
        mn = (v < mn) ? v : mn;
      }
      for (int off = 32; off > 0; off >>= 1) {
        unsigned long long o = __shfl_down(mn, off);
        mn = (o < mn) ? o : mn;
      }
      if ((t & 63) == 0) red[t >> 6] = mn;
      __syncthreads();
      if (t == 0) {
        unsigned long long w0 = red[0];
        for (int q = 1; q < 4; ++q) w0 = (red[q] < w0) ? red[q] : w0;
        t20[k] = (unsigned)(w0 & 0xFFFull);
        keyl[w0 & 0xFFFull] = ~0ull;
      }
      __syncthreads();
    }
    if (t < 64) {
      const float* ub = uT + (size_t)b*4096*64;
      float mx = -3.4e38f, s1 = 0.f, s2 = 0.f;
      #pragma unroll
      for (int k = 0; k < 20; ++k) {
        unsigned m = t20[k];
        float g = ub[(size_t)m*64 + t];
        mx = fmaxf(mx, g); s1 += g; s2 = fmaf(g, g, s2);
      }
      size_t ro = ((size_t)b*4096 + n)*64 + t;
      float v = vT[ro];
      stage[ro] = mx + v;
      double dv = (double)v;
      __hip_atomic_fetch_add(&k3bS1[b*64 + t], (double)s1 + 20.0*dv,
                             __ATOMIC_RELAXED, __HIP_MEMORY_SCOPE_AGENT);
      __hip_atomic_fetch_add(&k3bS2[b*64 + t], (double)s2 + 2.0*dv*(double)s1 + 20.0*dv*dv,
                             __ATOMIC_RELAXED, __HIP_MEMORY_SCOPE_AGENT);
    }
    __syncthreads();
  }
}

// ---------------------------------------------------------------------------
// K4: reduce partials -> mean/var per (b,o); normalize + leaky-ReLU.
// ---------------------------------------------------------------------------
__global__ __launch_bounds__(256) void k4_final(
    const float* __restrict__ stage,
    const double* __restrict__ pS1, const double* __restrict__ pS2,
    const double* __restrict__ k3bS1, const double* __restrict__ k3bS2,
    float* __restrict__ out)
{
  __shared__ double r1[4], r2[4];
  __shared__ float params[2];
  int bo = blockIdx.x;
  int b = bo >> 6, o = bo & 63;
  int t = threadIdx.x;
  double s1 = 0.0, s2 = 0.0;
  for (int j = t; j < 1024; j += 256) {
    s1 += pS1[(size_t)(b*1024 + j)*64 + o];
    s2 += pS2[(size_t)(b*1024 + j)*64 + o];
  }
  for (int off = 32; off > 0; off >>= 1) {
    s1 += __shfl_down(s1, off);
    s2 += __shfl_down(s2, off);
  }
  if ((t & 63) == 0) { r1[t >> 6] = s1; r2[t >> 6] = s2; }
  __syncthreads();
  if (t == 0) {
    double S1 = r1[0]+r1[1]+r1[2]+r1[3] + k3bS1[bo];
    double S2 = r2[0]+r2[1]+r2[2]+r2[3] + k3bS2[bo];
    double inv = 1.0 / (4096.0 * 20.0);
    double mean = S1 * inv;
    double var  = S2 * inv - mean * mean;
    params[0] = (float)mean;
    params[1] = (float)rsqrt(var + 1e-5);
  }
  __syncthreads();
  float mf = params[0], rs = params[1];
  for (int n = t; n < 4096; n += 256) {
    float y = (stage[((size_t)b*4096 + n)*64 + o] - mf) * rs;
    out[(size_t)bo*4096 + n] = (y >= 0.f) ? y : 0.2f * y;
  }
}

// ---------------------------------------------------------------------------
extern "C" void kernel_launch(void* const* d_in, const int* in_sizes, int n_in,
                              void* d_out, int out_size, void* d_ws, size_t ws_size,
                              hipStream_t stream)
{
  (void)in_sizes; (void)n_in; (void)out_size; (void)ws_size;
  const float* x = (const float*)d_in[0];   // (4,64,4096)
  const float* W = (const float*)d_in[1];   // (64,128)
  float* out = (float*)d_out;

  char* ws = (char*)d_ws;
  size_t off = 0;
  auto alloc = [&](size_t bytes) {
    char* p = ws + off;
    off = (off + bytes + 255) & ~(size_t)255;
    return p;
  };
  float*          uT       = (float*)         alloc((size_t)NROW*64*4);
  float*          vT       = (float*)         alloc((size_t)NROW*64*4);
  float*          xT       = (float*)         alloc((size_t)NROW*64*4);
  float*          stage    = (float*)         alloc((size_t)NROW*64*4);
  unsigned short* xh       = (unsigned short*)alloc((size_t)NROW*64*2);
  unsigned short* xl       = (unsigned short*)alloc((size_t)NROW*64*2);
  float*          xxf      = (float*)         alloc((size_t)NROW*4);
  double*         xxd      = (double*)        alloc((size_t)NROW*8);
  double*         pS1      = (double*)        alloc((size_t)4096*64*8);
  double*         pS2      = (double*)        alloc((size_t)4096*64*8);
  unsigned*       counts   = (unsigned*)      alloc((size_t)NROW*NSEG*4);
  // zeroed region (contiguous): slowcnt, k3bS1, k3bS2
  unsigned*       slowcnt  = (unsigned*)      alloc(256);
  double*         k3bS1    = (double*)        alloc(256*8);
  double*         k3bS2    = (double*)        alloc(256*8);
  unsigned*       slowlist = (unsigned*)      alloc((size_t)NROW*4);
  unsigned*       surv     = (unsigned*)      alloc((size_t)NROW*SROW*4);

  hipMemsetAsync(slowcnt, 0, 256 + 2048 + 2048, stream);

  k1_prep  <<<256,  256, 0, stream>>>(x, W, xT, xh, xl, xxf, xxd, uT, vT);
  k2_screen<<<512,  256, 0, stream>>>(xh, xl, xxf, counts, surv);
  k3_select<<<4096, 256, 0, stream>>>(xT, xxd, counts, surv, uT, vT,
                                      stage, pS1, pS2, slowcnt, slowlist);
  k3b_slow <<<128,  256, 0, stream>>>(xT, xxd, slowcnt, slowlist,
                                      uT, vT, stage, k3bS1, k3bS2);
  k4_final <<<256,  256, 0, stream>>>(stage, pS1, pS2, k3bS1, k3bS2, out);
}

// Round 5
// 223.998 us; speedup vs baseline: 1.1701x; 1.1701x over previous
//
#include <hip/hip_runtime.h>
#include <hip/hip_bf16.h>
#include <cstdint>
#include <cstddef>

// Problem constants (fixed by reference)
#define BB 4
#define NN 4096
#define NROW (BB*NN)          // 16384 rows
#define SEGW 32               // slots per (row, m-split) segment
#define NSEG 8                // m-splits
#define SROW (SEGW*NSEG)      // 256 survivor slots per row
// bf16-only screen: |w_approx - w_true| <= E = 1.25 (proven for ||x||^2<=140)
#define QPf 28.3f             // push threshold: 27 + E + slack
#define STRICT_Q 48537u       // q for w_approx < 25.8 = QP - 2E  (floor((25.8+69)*512))
#define DQ 1282u              // window: ceil(2*E*512)+2

typedef float v2f   __attribute__((ext_vector_type(2)));
typedef float f32x16 __attribute__((ext_vector_type(16)));
typedef short s16x8 __attribute__((ext_vector_type(8)));
typedef __bf16 bf16x8 __attribute__((ext_vector_type(8)));

__device__ __forceinline__ v2f pkfma(v2f a, v2f b, v2f c) {
  return __builtin_elementwise_fma(a, b, c);
}
__device__ __forceinline__ unsigned short f2bf(float f) {
  unsigned u = __float_as_uint(f);
  u += 0x7FFFu + ((u >> 16) & 1u);      // RNE (no NaN/Inf in data)
  return (unsigned short)(u >> 16);
}

// ---------------------------------------------------------------------------
// K1: prep. xT f32 [point][c]; xh bf16 [point][c]; xxf/xxd norms;
//     uT = W1.x, vT = (W2-W1).x  [point][o]  (weights in registers)
// ---------------------------------------------------------------------------
__global__ __launch_bounds__(256) void k1_prep(
    const float* __restrict__ x, const float* __restrict__ W,
    float* __restrict__ xT, unsigned short* __restrict__ xh,
    float* __restrict__ xxf, double* __restrict__ xxd,
    float* __restrict__ uT, float* __restrict__ vT)
{
  __shared__ float xc[64][65];   // [c][n]
  __shared__ float xr[64][68];   // [n][c]
  __shared__ float w1[64][65];
  __shared__ float wd[64][65];
  int t = threadIdx.x;
  int b  = blockIdx.x >> 6;
  int n0 = (blockIdx.x & 63) * 64;

  for (int i = t; i < 4096; i += 256) {
    int o = i >> 6, c = i & 63;
    float a = W[o*128 + c];
    w1[o][c] = a;
    wd[o][c] = W[o*128 + 64 + c] - a;
  }
  for (int i = t; i < 4096; i += 256) {
    int c = i >> 6, n = i & 63;
    xc[c][n] = x[((size_t)b*64 + c)*4096 + n0 + n];
  }
  __syncthreads();

  for (int i = t; i < 4096; i += 256) {
    int n = i >> 6, c = i & 63;
    float v = xc[c][n];
    xr[n][c] = v;
    size_t pi = ((size_t)b*4096 + n0 + n)*64 + c;
    xT[pi] = v;
    xh[pi] = f2bf(v);
  }
  if (t < 64) {
    int n = t;
    float s0=0,s1=0,s2=0,s3=0; double sd=0.0;
    for (int c = 0; c < 64; c += 4) {
      float a0=xc[c][n],a1=xc[c+1][n],a2=xc[c+2][n],a3=xc[c+3][n];
      s0=fmaf(a0,a0,s0); s1=fmaf(a1,a1,s1); s2=fmaf(a2,a2,s2); s3=fmaf(a3,a3,s3);
      sd += (double)a0*a0 + (double)a1*a1 + (double)a2*a2 + (double)a3*a3;
    }
    xxf[(size_t)b*4096 + n0 + n] = (s0+s1)+(s2+s3);
    xxd[(size_t)b*4096 + n0 + n] = sd;
  }
  v2f w1r[32], wdr[32];
  int o = t & 63;
  #pragma unroll
  for (int j = 0; j < 32; ++j) {
    w1r[j].x = w1[o][2*j]; w1r[j].y = w1[o][2*j+1];
    wdr[j].x = wd[o][2*j]; wdr[j].y = wd[o][2*j+1];
  }
  __syncthreads();

  for (int i = t; i < 4096; i += 256) {
    int n = i >> 6;
    v2f au; au.x=0.f; au.y=0.f;
    v2f av; av.x=0.f; av.y=0.f;
    #pragma unroll
    for (int cb = 0; cb < 16; ++cb) {
      float4 xv = *(const float4*)&xr[n][cb*4];
      v2f p0; p0.x = xv.x; p0.y = xv.y;
      v2f p1; p1.x = xv.z; p1.y = xv.w;
      au = pkfma(w1r[2*cb],   p0, au);
      au = pkfma(w1r[2*cb+1], p1, au);
      av = pkfma(wdr[2*cb],   p0, av);
      av = pkfma(wdr[2*cb+1], p1, av);
    }
    size_t idx = ((size_t)b*4096 + n0 + n)*64 + o;
    uT[idx] = au.x + au.y;
    vT[idx] = av.x + av.y;
  }
}

// ---------------------------------------------------------------------------
// K2: bf16 MFMA Gram screen, NO LDS staging (B-frags direct from global/L1,
// identical fragment layout as A). LDS = segcnt[256] only -> ~5 waves/SIMD;
// per-taker ds_add_rtn latency hides across independent (barrier-free) waves.
// Grid = 64 n-blocks x 8 m-splits; block = 256 rows x 512 m.
// ---------------------------------------------------------------------------
__global__ __launch_bounds__(256) void k2_screen(
    const unsigned short* __restrict__ xh, const float* __restrict__ xxf,
    unsigned* __restrict__ counts, unsigned* __restrict__ surv)
{
  __shared__ unsigned segcnt[256];
  int t  = threadIdx.x;
  int nb = blockIdx.x >> 3;
  int ms = blockIdx.x & 7;
  int row0 = nb * 256;
  int b = row0 >> 12;
  int mbase = ms * 512;
  const unsigned short* xhB = xh + ((size_t)b*4096)*64;

  segcnt[t] = 0u;

  int wv = t >> 6, lane = t & 63;
  int lr = lane & 31, oct = lane >> 5;

  // A-fragments in registers (A,B fed with identical lane->element maps,
  // so any within-K ordering assumption cancels in the dot product)
  s16x8 ah[2][4];
  #pragma unroll
  for (int nt = 0; nt < 2; ++nt)
    #pragma unroll
    for (int ks = 0; ks < 4; ++ks)
      ah[nt][ks] = *(const s16x8*)(xh +
        ((size_t)(row0 + wv*64 + nt*32 + lr))*64 + ks*16 + oct*8);
  __syncthreads();

  for (int mt = 0; mt < 16; ++mt) {
    int m0 = mbase + mt*32;
    s16x8 bh[4];
    #pragma unroll
    for (int ks = 0; ks < 4; ++ks)
      bh[ks] = *(const s16x8*)(xhB + (size_t)(m0 + lr)*64 + ks*16 + oct*8);

    f32x16 a0, a1;
    #pragma unroll
    for (int i = 0; i < 16; ++i) { a0[i] = 0.f; a1[i] = 0.f; }
    #pragma unroll
    for (int ks = 0; ks < 4; ++ks) {
      bf16x8 AH0 = __builtin_bit_cast(bf16x8, ah[0][ks]);
      bf16x8 AH1 = __builtin_bit_cast(bf16x8, ah[1][ks]);
      bf16x8 BH  = __builtin_bit_cast(bf16x8, bh[ks]);
      a0 = __builtin_amdgcn_mfma_f32_32x32x16_bf16(AH0, BH, a0, 0, 0, 0);
      a1 = __builtin_amdgcn_mfma_f32_32x32x16_bf16(AH1, BH, a1, 0, 0, 0);
    }

    // epilogue: w = xx_m - 2*S ; LDS-atomic slot, fire-and-forget store
    int mg = m0 + lr;
    float xxm = xxf[b*4096 + mg];
    #pragma unroll
    for (int i = 0; i < 16; ++i) {
      const int base_i = (i & 3) + 8*(i >> 2);   // C/D row map (measured)
      {
        float w = fmaf(-2.0f, a0[i], xxm);
        if (w < QPf) {
          int rloc = wv*64 + base_i + 4*oct;
          int qi = (int)((w + 69.0f) * 512.0f);
          qi = min(max(qi, 0), 65535);
          unsigned key = ((unsigned)qi << 12) | (unsigned)mg;
          unsigned slot = atomicAdd(&segcnt[rloc], 1u);
          if (slot < SEGW) surv[(size_t)(row0 + rloc)*SROW + ms*SEGW + slot] = key;
        }
      }
      {
        float w = fmaf(-2.0f, a1[i], xxm);
        if (w < QPf) {
          int rloc = wv*64 + 32 + base_i + 4*oct;
          int qi = (int)((w + 69.0f) * 512.0f);
          qi = min(max(qi, 0), 65535);
          unsigned key = ((unsigned)qi << 12) | (unsigned)mg;
          unsigned slot = atomicAdd(&segcnt[rloc], 1u);
          if (slot < SEGW) surv[(size_t)(row0 + rloc)*SROW + ms*SEGW + slot] = key;
        }
      }
    }
  }
  __syncthreads();
  counts[(size_t)(row0 + t)*NSEG + ms] = segcnt[t];   // unique writer
}

// ---------------------------------------------------------------------------
// K3: per-row wave. 8 segments of 32 slots -> 4 key regs (segment pair per
// lane-half); strict check; 16-iter q-bisection; window select (superset of
// true top-20); f64 rescore; bitonic sort; gather/max epilogue.
// ---------------------------------------------------------------------------
__global__ __launch_bounds__(256) void k3_select(
    const float* __restrict__ xT, const double* __restrict__ xxd,
    const unsigned* __restrict__ counts, const unsigned* __restrict__ surv,
    const float* __restrict__ uT, const float* __restrict__ vT,
    float* __restrict__ stage, double* __restrict__ pS1, double* __restrict__ pS2,
    unsigned* __restrict__ slowcnt, unsigned* __restrict__ slowlist)
{
  __shared__ unsigned candm[4][64];
  __shared__ double ps1[4][64], ps2[4][64];
  int wv = threadIdx.x >> 6, lane = threadIdx.x & 63;
  int row = blockIdx.x * 4 + wv;
  int b = row >> 12, n = row & 4095;

  double s1t = 0.0, s2t = 0.0;

  uint4 c0 = *(const uint4*)&counts[(size_t)row*NSEG];
  uint4 c1 = *(const uint4*)&counts[(size_t)row*NSEG + 4];
  bool slow = (c0.x > SEGW) | (c0.y > SEGW) | (c0.z > SEGW) | (c0.w > SEGW)
            | (c1.x > SEGW) | (c1.y > SEGW) | (c1.z > SEGW) | (c1.w > SEGW);

  int half = lane >> 5, idx = lane & 31;
  unsigned sc[4];
  sc[0] = half ? c0.y : c0.x;
  sc[1] = half ? c0.w : c0.z;
  sc[2] = half ? c1.y : c1.x;
  sc[3] = half ? c1.w : c1.z;

  unsigned key[4];
  #pragma unroll
  for (int s = 0; s < 4; ++s) {
    int sg = 2*s + half;
    key[s] = (!slow && idx < (int)sc[s])
           ? surv[(size_t)row*SROW + sg*SEGW + idx] : 0xFFFFFFFFu;
  }

  int strictc = 0;
  #pragma unroll
  for (int s = 0; s < 4; ++s)
    strictc += __popcll(__ballot(key[s] < (STRICT_Q << 12)));
  slow = slow || (strictc < 20);

  int sel = 0;
  if (!slow) {
    // bisect on 16-bit q field: find q20 (q of 20th-smallest key)
    unsigned lo = 0u, hi = 1u << 16;
    for (int it = 0; it < 16; ++it) {
      unsigned mid = (lo + hi) >> 1;
      unsigned Tm = mid << 12;
      int c = 0;
      #pragma unroll
      for (int s = 0; s < 4; ++s)
        c += __popcll(__ballot(key[s] < Tm));
      if (c >= 20) hi = mid; else lo = mid;
    }
    unsigned T = (lo + DQ) << 12;    // window covers q20 .. q20+DQ-1
    int c = 0;
    #pragma unroll
    for (int s = 0; s < 4; ++s)
      c += __popcll(__ballot(key[s] < T));
    sel = c;
    if (sel > 64) {
      slow = true;
    } else {
      int base = 0;
      #pragma unroll
      for (int s = 0; s < 4; ++s) {
        unsigned long long mask = __ballot(key[s] < T);
        if (key[s] < T) {
          int pos = base + __popcll(mask & ((1ull << lane) - 1ull));
          candm[wv][pos] = key[s] & 0xFFFu;
        }
        base += __popcll(mask);
      }
    }
  }

  if (!slow) {
    __builtin_amdgcn_wave_barrier();
    unsigned long long k64 = ~0ull;
    if (lane < sel) {
      int m = (int)candm[wv][lane];
      const float* pn = xT + ((size_t)b*4096 + n)*64;
      const float* pm = xT + ((size_t)b*4096 + m)*64;
      double acc = 0.0;
      #pragma unroll 4
      for (int c2 = 0; c2 < 64; c2 += 4) {
        float4 a  = *(const float4*)(pn + c2);
        float4 bf = *(const float4*)(pm + c2);
        acc = fma((double)a.x, (double)bf.x, acc);
        acc = fma((double)a.y, (double)bf.y, acc);
        acc = fma((double)a.z, (double)bf.z, acc);
        acc = fma((double)a.w, (double)bf.w, acc);
      }
      double d = xxd[(size_t)b*4096 + n] + xxd[(size_t)b*4096 + m] - 2.0*acc;
      d = fmax(d, 0.0);
      k64 = (((unsigned long long)__double_as_longlong(d)) & ~0xFFFull)
          | (unsigned long long)m;            // tie -> lower index (lax.top_k)
    }
    #pragma unroll
    for (int kk = 2; kk <= 64; kk <<= 1) {
      #pragma unroll
      for (int j = kk >> 1; j > 0; j >>= 1) {
        unsigned long long o = __shfl_xor(k64, j);
        bool up    = ((lane & kk) == 0);
        bool lower = ((lane & j) == 0);
        unsigned long long mn = (k64 < o) ? k64 : o;
        unsigned long long mx = (k64 < o) ? o : k64;
        k64 = (lower == up) ? mn : mx;
      }
    }
    int mlow = (int)(k64 & 0xFFFull);          // lanes 0..19 = top-20
    const float* ub = uT + (size_t)b*4096*64;
    float mx = -3.4e38f, s1 = 0.f, s2 = 0.f;
    #pragma unroll
    for (int k = 0; k < 20; ++k) {
      int m = __shfl(mlow, k);
      float g = ub[(size_t)m*64 + lane];
      mx = fmaxf(mx, g); s1 += g; s2 = fmaf(g, g, s2);
    }
    size_t ro = ((size_t)b*4096 + n)*64 + lane;
    float v = vT[ro];
    stage[ro] = mx + v;
    double dv = (double)v;
    s1t = (double)s1 + 20.0*dv;
    s2t = (double)s2 + 2.0*dv*(double)s1 + 20.0*dv*dv;
  } else {
    if (lane == 0) { unsigned i = atomicAdd(slowcnt, 1u); slowlist[i] = row; }
  }

  ps1[wv][lane] = s1t; ps2[wv][lane] = s2t;
  __syncthreads();
  if (wv == 0) {
    pS1[(size_t)blockIdx.x*64 + lane] = ps1[0][lane]+ps1[1][lane]+ps1[2][lane]+ps1[3][lane];
    pS2[(size_t)blockIdx.x*64 + lane] = ps2[0][lane]+ps2[1][lane]+ps2[2][lane]+ps2[3][lane];
  }
}

// ---------------------------------------------------------------------------
// K3b: slow path (expected ~50-200 rows): full f64 scan + 20x extraction.
// ---------------------------------------------------------------------------
__global__ __launch_bounds__(256) void k3b_slow(
    const float* __restrict__ xT, const double* __restrict__ xxd,
    const unsigned* __restrict__ slowcnt, const unsigned* __restrict__ slowlist,
    const float* __restrict__ uT, const float* __restrict__ vT,
    float* __restrict__ stage, double* __restrict__ k3bS1, double* __restrict__ k3bS2)
{
  __shared__ unsigned long long keyl[4096];
  __shared__ unsigned long long red[4];
  __shared__ unsigned t20[20];
  unsigned nslow = *slowcnt;
  int t = threadIdx.x;
  for (unsigned ii = blockIdx.x; ii < nslow; ii += gridDim.x) {
    int row = (int)slowlist[ii];
    int b = row >> 12, n = row & 4095;
    const float* pn = xT + ((size_t)b*4096 + n)*64;
    double xxn = xxd[(size_t)b*4096 + n];
    for (int m = t; m < 4096; m += 256) {
      const float* pm = xT + ((size_t)b*4096 + m)*64;
      double acc = 0.0;
      #pragma unroll 4
      for (int c = 0; c < 64; c += 4) {
        float4 a  = *(const float4*)(pn + c);
        float4 bf = *(const float4*)(pm + c);
        acc = fma((double)a.x, (double)bf.x, acc);
        acc = fma((double)a.y, (double)bf.y, acc);
        acc = fma((double)a.z, (double)bf.z, acc);
        acc = fma((double)a.w, (double)bf.w, acc);
      }
      double d = fmax(xxn + xxd[(size_t)b*4096 + m] - 2.0*acc, 0.0);
      keyl[m] = (((unsigned long long)__double_as_longlong(d)) & ~0xFFFull)
              | (unsigned long long)m;
    }
    __syncthreads();
    for (int k = 0; k < 20; ++k) {
      unsigned long long mn = ~0ull;
      #pragma unroll
      for (int s = 0; s < 16; ++s) {
        unsigned long long v = keyl[t + s*256];
        mn = (v < mn) ? v : mn;
      }
      for (int off = 32; off > 0; off >>= 1) {
        unsigned long long o = __shfl_down(mn, off);
        mn = (o < mn) ? o : mn;
      }
      if ((t & 63) == 0) red[t >> 6] = mn;
      __syncthreads();
      if (t == 0) {
        unsigned long long w0 = red[0];
        for (int q = 1; q < 4; ++q) w0 = (red[q] < w0) ? red[q] : w0;
        t20[k] = (unsigned)(w0 & 0xFFFull);
        keyl[w0 & 0xFFFull] = ~0ull;
      }
      __syncthreads();
    }
    if (t < 64) {
      const float* ub = uT + (size_t)b*4096*64;
      float mx = -3.4e38f, s1 = 0.f, s2 = 0.f;
      #pragma unroll
      for (int k = 0; k < 20; ++k) {
        unsigned m = t20[k];
        float g = ub[(size_t)m*64 + t];
        mx = fmaxf(mx, g); s1 += g; s2 = fmaf(g, g, s2);
      }
      size_t ro = ((size_t)b*4096 + n)*64 + t;
      float v = vT[ro];
      stage[ro] = mx + v;
      double dv = (double)v;
      __hip_atomic_fetch_add(&k3bS1[b*64 + t], (double)s1 + 20.0*dv,
                             __ATOMIC_RELAXED, __HIP_MEMORY_SCOPE_AGENT);
      __hip_atomic_fetch_add(&k3bS2[b*64 + t], (double)s2 + 2.0*dv*(double)s1 + 20.0*dv*dv,
                             __ATOMIC_RELAXED, __HIP_MEMORY_SCOPE_AGENT);
    }
    __syncthreads();
  }
}

// ---------------------------------------------------------------------------
// K4: reduce partials -> mean/var per (b,o); normalize + leaky-ReLU.
// ---------------------------------------------------------------------------
__global__ __launch_bounds__(256) void k4_final(
    const float* __restrict__ stage,
    const double* __restrict__ pS1, const double* __restrict__ pS2,
    const double* __restrict__ k3bS1, const double* __restrict__ k3bS2,
    float* __restrict__ out)
{
  __shared__ double r1[4], r2[4];
  __shared__ float params[2];
  int bo = blockIdx.x;
  int b = bo >> 6, o = bo & 63;
  int t = threadIdx.x;
  double s1 = 0.0, s2 = 0.0;
  for (int j = t; j < 1024; j += 256) {
    s1 += pS1[(size_t)(b*1024 + j)*64 + o];
    s2 += pS2[(size_t)(b*1024 + j)*64 + o];
  }
  for (int off = 32; off > 0; off >>= 1) {
    s1 += __shfl_down(s1, off);
    s2 += __shfl_down(s2, off);
  }
  if ((t & 63) == 0) { r1[t >> 6] = s1; r2[t >> 6] = s2; }
  __syncthreads();
  if (t == 0) {
    double S1 = r1[0]+r1[1]+r1[2]+r1[3] + k3bS1[bo];
    double S2 = r2[0]+r2[1]+r2[2]+r2[3] + k3bS2[bo];
    double inv = 1.0 / (4096.0 * 20.0);
    double mean = S1 * inv;
    double var  = S2 * inv - mean * mean;
    params[0] = (float)mean;
    params[1] = (float)rsqrt(var + 1e-5);
  }
  __syncthreads();
  float mf = params[0], rs = params[1];
  for (int n = t; n < 4096; n += 256) {
    float y = (stage[((size_t)b*4096 + n)*64 + o] - mf) * rs;
    out[(size_t)bo*4096 + n] = (y >= 0.f) ? y : 0.2f * y;
  }
}

// ---------------------------------------------------------------------------
extern "C" void kernel_launch(void* const* d_in, const int* in_sizes, int n_in,
                              void* d_out, int out_size, void* d_ws, size_t ws_size,
                              hipStream_t stream)
{
  (void)in_sizes; (void)n_in; (void)out_size; (void)ws_size;
  const float* x = (const float*)d_in[0];   // (4,64,4096)
  const float* W = (const float*)d_in[1];   // (64,128)
  float* out = (float*)d_out;

  char* ws = (char*)d_ws;
  size_t off = 0;
  auto alloc = [&](size_t bytes) {
    char* p = ws + off;
    off = (off + bytes + 255) & ~(size_t)255;
    return p;
  };
  float*          uT       = (float*)         alloc((size_t)NROW*64*4);
  float*          vT       = (float*)         alloc((size_t)NROW*64*4);
  float*          xT       = (float*)         alloc((size_t)NROW*64*4);
  float*          stage    = (float*)         alloc((size_t)NROW*64*4);
  unsigned short* xh       = (unsigned short*)alloc((size_t)NROW*64*2);
  float*          xxf      = (float*)         alloc((size_t)NROW*4);
  double*         xxd      = (double*)        alloc((size_t)NROW*8);
  double*         pS1      = (double*)        alloc((size_t)4096*64*8);
  double*         pS2      = (double*)        alloc((size_t)4096*64*8);
  unsigned*       counts   = (unsigned*)      alloc((size_t)NROW*NSEG*4);
  // zeroed region (contiguous): slowcnt, k3bS1, k3bS2
  unsigned*       slowcnt  = (unsigned*)      alloc(256);
  double*         k3bS1    = (double*)        alloc(256*8);
  double*         k3bS2    = (double*)        alloc(256*8);
  unsigned*       slowlist = (unsigned*)      alloc((size_t)NROW*4);
  unsigned*       surv     = (unsigned*)      alloc((size_t)NROW*SROW*4);

  hipMemsetAsync(slowcnt, 0, 256 + 2048 + 2048, stream);

  k1_prep  <<<256,  256, 0, stream>>>(x, W, xT, xh, xxf, xxd, uT, vT);
  k2_screen<<<512,  256, 0, stream>>>(xh, xxf, counts, surv);
  k3_select<<<4096, 256, 0, stream>>>(xT, xxd, counts, surv, uT, vT,
                                      stage, pS1, pS2, slowcnt, slowlist);
  k3b_slow <<<256,  256, 0, stream>>>(xT, xxd, slowcnt, slowlist,
                                      uT, vT, stage, k3bS1, k3bS2);
  k4_final <<<256,  256, 0, stream>>>(stage, pS1, pS2, k3bS1, k3bS2, out);
}

// Round 6
// 184.005 us; speedup vs baseline: 1.4244x; 1.2173x over previous
//
#include <hip/hip_runtime.h>
#include <hip/hip_bf16.h>
#include <cstdint>
#include <cstddef>

// Problem constants (fixed by reference)
#define BB 4
#define NN 4096
#define NROW (BB*NN)          // 16384 rows
#define SEGW 64               // slots per (row, m-split) segment
#define NSEG 8                // m-splits
#define SROW (SEGW*NSEG)      // 512 survivor slots per row
// bf16-only screen: |w_approx - w_true| <= E = 1.25 (proven for ||x||^2<=140)
#define QPf 28.45f            // push threshold: strict(25.8) + 2E + slack
#define STRICT_Q 48537u       // q for w_approx < 25.8  (floor((25.8+69)*512))
#define DQ 1282u              // window: ceil(2*E*512)+2

typedef float v2f   __attribute__((ext_vector_type(2)));
typedef float f32x16 __attribute__((ext_vector_type(16)));
typedef short s16x8 __attribute__((ext_vector_type(8)));
typedef __bf16 bf16x8 __attribute__((ext_vector_type(8)));

__device__ __forceinline__ v2f pkfma(v2f a, v2f b, v2f c) {
  return __builtin_elementwise_fma(a, b, c);
}
__device__ __forceinline__ unsigned short f2bf(float f) {
  unsigned u = __float_as_uint(f);
  u += 0x7FFFu + ((u >> 16) & 1u);      // RNE (no NaN/Inf in data)
  return (unsigned short)(u >> 16);
}

// ---------------------------------------------------------------------------
// K1: prep. xT f32 [point][c]; xh bf16 [point][c]; xxf/xxd norms;
//     uT = W1.x, vT = (W2-W1).x  [point][o]  (weights in registers)
// ---------------------------------------------------------------------------
__global__ __launch_bounds__(256) void k1_prep(
    const float* __restrict__ x, const float* __restrict__ W,
    float* __restrict__ xT, unsigned short* __restrict__ xh,
    float* __restrict__ xxf, double* __restrict__ xxd,
    float* __restrict__ uT, float* __restrict__ vT)
{
  __shared__ float xc[64][65];   // [c][n]
  __shared__ float xr[64][68];   // [n][c]
  __shared__ float w1[64][65];
  __shared__ float wd[64][65];
  int t = threadIdx.x;
  int b  = blockIdx.x >> 6;
  int n0 = (blockIdx.x & 63) * 64;

  for (int i = t; i < 4096; i += 256) {
    int o = i >> 6, c = i & 63;
    float a = W[o*128 + c];
    w1[o][c] = a;
    wd[o][c] = W[o*128 + 64 + c] - a;
  }
  for (int i = t; i < 4096; i += 256) {
    int c = i >> 6, n = i & 63;
    xc[c][n] = x[((size_t)b*64 + c)*4096 + n0 + n];
  }
  __syncthreads();

  for (int i = t; i < 4096; i += 256) {
    int n = i >> 6, c = i & 63;
    float v = xc[c][n];
    xr[n][c] = v;
    size_t pi = ((size_t)b*4096 + n0 + n)*64 + c;
    xT[pi] = v;
    xh[pi] = f2bf(v);
  }
  if (t < 64) {
    int n = t;
    float s0=0,s1=0,s2=0,s3=0; double sd=0.0;
    for (int c = 0; c < 64; c += 4) {
      float a0=xc[c][n],a1=xc[c+1][n],a2=xc[c+2][n],a3=xc[c+3][n];
      s0=fmaf(a0,a0,s0); s1=fmaf(a1,a1,s1); s2=fmaf(a2,a2,s2); s3=fmaf(a3,a3,s3);
      sd += (double)a0*a0 + (double)a1*a1 + (double)a2*a2 + (double)a3*a3;
    }
    xxf[(size_t)b*4096 + n0 + n] = (s0+s1)+(s2+s3);
    xxd[(size_t)b*4096 + n0 + n] = sd;
  }
  v2f w1r[32], wdr[32];
  int o = t & 63;
  #pragma unroll
  for (int j = 0; j < 32; ++j) {
    w1r[j].x = w1[o][2*j]; w1r[j].y = w1[o][2*j+1];
    wdr[j].x = wd[o][2*j]; wdr[j].y = wd[o][2*j+1];
  }
  __syncthreads();

  for (int i = t; i < 4096; i += 256) {
    int n = i >> 6;
    v2f au; au.x=0.f; au.y=0.f;
    v2f av; av.x=0.f; av.y=0.f;
    #pragma unroll
    for (int cb = 0; cb < 16; ++cb) {
      float4 xv = *(const float4*)&xr[n][cb*4];
      v2f p0; p0.x = xv.x; p0.y = xv.y;
      v2f p1; p1.x = xv.z; p1.y = xv.w;
      au = pkfma(w1r[2*cb],   p0, au);
      au = pkfma(w1r[2*cb+1], p1, au);
      av = pkfma(wdr[2*cb],   p0, av);
      av = pkfma(wdr[2*cb+1], p1, av);
    }
    size_t idx = ((size_t)b*4096 + n0 + n)*64 + o;
    uT[idx] = au.x + au.y;
    vT[idx] = av.x + av.y;
  }
}

// ---------------------------------------------------------------------------
// K2: bf16 MFMA Gram screen, NO LDS staging (B-frags direct from global/L1,
// identical fragment layout as A). LDS = segcnt[256] only -> high occupancy;
// per-taker ds_add_rtn latency hides across independent (barrier-free) waves.
// Grid = 64 n-blocks x 8 m-splits; block = 256 rows x 512 m.
// ---------------------------------------------------------------------------
__global__ __launch_bounds__(256) void k2_screen(
    const unsigned short* __restrict__ xh, const float* __restrict__ xxf,
    unsigned* __restrict__ counts, unsigned* __restrict__ surv)
{
  __shared__ unsigned segcnt[256];
  int t  = threadIdx.x;
  int nb = blockIdx.x >> 3;
  int ms = blockIdx.x & 7;
  int row0 = nb * 256;
  int b = row0 >> 12;
  int mbase = ms * 512;
  const unsigned short* xhB = xh + ((size_t)b*4096)*64;

  segcnt[t] = 0u;

  int wv = t >> 6, lane = t & 63;
  int lr = lane & 31, oct = lane >> 5;

  // A-fragments in registers (A,B fed with identical lane->element maps,
  // so any within-K ordering assumption cancels in the dot product)
  s16x8 ah[2][4];
  #pragma unroll
  for (int nt = 0; nt < 2; ++nt)
    #pragma unroll
    for (int ks = 0; ks < 4; ++ks)
      ah[nt][ks] = *(const s16x8*)(xh +
        ((size_t)(row0 + wv*64 + nt*32 + lr))*64 + ks*16 + oct*8);
  __syncthreads();

  for (int mt = 0; mt < 16; ++mt) {
    int m0 = mbase + mt*32;
    s16x8 bh[4];
    #pragma unroll
    for (int ks = 0; ks < 4; ++ks)
      bh[ks] = *(const s16x8*)(xhB + (size_t)(m0 + lr)*64 + ks*16 + oct*8);

    f32x16 a0, a1;
    #pragma unroll
    for (int i = 0; i < 16; ++i) { a0[i] = 0.f; a1[i] = 0.f; }
    #pragma unroll
    for (int ks = 0; ks < 4; ++ks) {
      bf16x8 AH0 = __builtin_bit_cast(bf16x8, ah[0][ks]);
      bf16x8 AH1 = __builtin_bit_cast(bf16x8, ah[1][ks]);
      bf16x8 BH  = __builtin_bit_cast(bf16x8, bh[ks]);
      a0 = __builtin_amdgcn_mfma_f32_32x32x16_bf16(AH0, BH, a0, 0, 0, 0);
      a1 = __builtin_amdgcn_mfma_f32_32x32x16_bf16(AH1, BH, a1, 0, 0, 0);
    }

    // epilogue: w = xx_m - 2*S ; LDS-atomic slot, fire-and-forget store
    int mg = m0 + lr;
    float xxm = xxf[b*4096 + mg];
    #pragma unroll
    for (int i = 0; i < 16; ++i) {
      const int base_i = (i & 3) + 8*(i >> 2);   // C/D row map (measured)
      {
        float w = fmaf(-2.0f, a0[i], xxm);
        if (w < QPf) {
          int rloc = wv*64 + base_i + 4*oct;
          int qi = (int)((w + 69.0f) * 512.0f);
          qi = min(max(qi, 0), 65535);
          unsigned key = ((unsigned)qi << 12) | (unsigned)mg;
          unsigned slot = atomicAdd(&segcnt[rloc], 1u);
          if (slot < SEGW) surv[(size_t)(row0 + rloc)*SROW + ms*SEGW + slot] = key;
        }
      }
      {
        float w = fmaf(-2.0f, a1[i], xxm);
        if (w < QPf) {
          int rloc = wv*64 + 32 + base_i + 4*oct;
          int qi = (int)((w + 69.0f) * 512.0f);
          qi = min(max(qi, 0), 65535);
          unsigned key = ((unsigned)qi << 12) | (unsigned)mg;
          unsigned slot = atomicAdd(&segcnt[rloc], 1u);
          if (slot < SEGW) surv[(size_t)(row0 + rloc)*SROW + ms*SEGW + slot] = key;
        }
      }
    }
  }
  __syncthreads();
  counts[(size_t)(row0 + t)*NSEG + ms] = segcnt[t];   // unique writer
}

// ---------------------------------------------------------------------------
// K3: per-row wave. 8 segments x 64 slots -> key[8]; strict check; 16-iter
// q-bisection; window select (superset of true top-20); f64 rescore;
// bitonic sort; gather/max epilogue. Partial sums -> pS1/pS2.
// ---------------------------------------------------------------------------
__global__ __launch_bounds__(256) void k3_select(
    const float* __restrict__ xT, const double* __restrict__ xxd,
    const unsigned* __restrict__ counts, const unsigned* __restrict__ surv,
    const float* __restrict__ uT, const float* __restrict__ vT,
    float* __restrict__ stage, double* __restrict__ pS1, double* __restrict__ pS2,
    unsigned* __restrict__ slowcnt, unsigned* __restrict__ slowlist)
{
  __shared__ unsigned candm[4][64];
  __shared__ double ps1[4][64], ps2[4][64];
  int wv = threadIdx.x >> 6, lane = threadIdx.x & 63;
  int row = blockIdx.x * 4 + wv;
  int b = row >> 12, n = row & 4095;

  double s1t = 0.0, s2t = 0.0;

  uint4 c0 = *(const uint4*)&counts[(size_t)row*NSEG];
  uint4 c1 = *(const uint4*)&counts[(size_t)row*NSEG + 4];
  unsigned segc[8] = {c0.x, c0.y, c0.z, c0.w, c1.x, c1.y, c1.z, c1.w};
  bool slow = false;
  #pragma unroll
  for (int s = 0; s < 8; ++s) slow = slow || (segc[s] > (unsigned)SEGW);

  unsigned key[8];
  #pragma unroll
  for (int s = 0; s < 8; ++s)
    key[s] = (!slow && lane < (int)segc[s])
           ? surv[(size_t)row*SROW + s*SEGW + lane] : 0xFFFFFFFFu;

  int strictc = 0;
  #pragma unroll
  for (int s = 0; s < 8; ++s)
    strictc += __popcll(__ballot(key[s] < (STRICT_Q << 12)));
  slow = slow || (strictc < 20);

  int sel = 0;
  if (!slow) {
    // bisect on 16-bit q field: find q20 (q of 20th-smallest key)
    unsigned lo = 0u, hi = 1u << 16;
    for (int it = 0; it < 16; ++it) {
      unsigned mid = (lo + hi) >> 1;
      unsigned Tm = mid << 12;
      int c = 0;
      #pragma unroll
      for (int s = 0; s < 8; ++s)
        c += __popcll(__ballot(key[s] < Tm));
      if (c >= 20) hi = mid; else lo = mid;
    }
    unsigned T = (lo + DQ) << 12;    // window covers q20 .. q20+DQ-1
    int c = 0;
    #pragma unroll
    for (int s = 0; s < 8; ++s)
      c += __popcll(__ballot(key[s] < T));
    sel = c;
    if (sel > 64) {
      slow = true;
    } else {
      int base = 0;
      #pragma unroll
      for (int s = 0; s < 8; ++s) {
        unsigned long long mask = __ballot(key[s] < T);
        if (key[s] < T) {
          int pos = base + __popcll(mask & ((1ull << lane) - 1ull));
          candm[wv][pos] = key[s] & 0xFFFu;
        }
        base += __popcll(mask);
      }
    }
  }

  if (!slow) {
    __builtin_amdgcn_wave_barrier();
    unsigned long long k64 = ~0ull;
    if (lane < sel) {
      int m = (int)candm[wv][lane];
      const float* pn = xT + ((size_t)b*4096 + n)*64;
      const float* pm = xT + ((size_t)b*4096 + m)*64;
      double acc = 0.0;
      #pragma unroll 4
      for (int c2 = 0; c2 < 64; c2 += 4) {
        float4 a  = *(const float4*)(pn + c2);
        float4 bf = *(const float4*)(pm + c2);
        acc = fma((double)a.x, (double)bf.x, acc);
        acc = fma((double)a.y, (double)bf.y, acc);
        acc = fma((double)a.z, (double)bf.z, acc);
        acc = fma((double)a.w, (double)bf.w, acc);
      }
      double d = xxd[(size_t)b*4096 + n] + xxd[(size_t)b*4096 + m] - 2.0*acc;
      d = fmax(d, 0.0);
      k64 = (((unsigned long long)__double_as_longlong(d)) & ~0xFFFull)
          | (unsigned long long)m;            // tie -> lower index (lax.top_k)
    }
    #pragma unroll
    for (int kk = 2; kk <= 64; kk <<= 1) {
      #pragma unroll
      for (int j = kk >> 1; j > 0; j >>= 1) {
        unsigned long long o = __shfl_xor(k64, j);
        bool up    = ((lane & kk) == 0);
        bool lower = ((lane & j) == 0);
        unsigned long long mn = (k64 < o) ? k64 : o;
        unsigned long long mx = (k64 < o) ? o : k64;
        k64 = (lower == up) ? mn : mx;
      }
    }
    int mlow = (int)(k64 & 0xFFFull);          // lanes 0..19 = top-20
    const float* ub = uT + (size_t)b*4096*64;
    float mx = -3.4e38f, s1 = 0.f, s2 = 0.f;
    #pragma unroll
    for (int k = 0; k < 20; ++k) {
      int m = __shfl(mlow, k);
      float g = ub[(size_t)m*64 + lane];
      mx = fmaxf(mx, g); s1 += g; s2 = fmaf(g, g, s2);
    }
    size_t ro = ((size_t)b*4096 + n)*64 + lane;
    float v = vT[ro];
    stage[ro] = mx + v;
    double dv = (double)v;
    s1t = (double)s1 + 20.0*dv;
    s2t = (double)s2 + 2.0*dv*(double)s1 + 20.0*dv*dv;
  } else {
    if (lane == 0) { unsigned i = atomicAdd(slowcnt, 1u); slowlist[i] = row; }
  }

  ps1[wv][lane] = s1t; ps2[wv][lane] = s2t;
  __syncthreads();
  if (wv == 0) {
    pS1[(size_t)blockIdx.x*64 + lane] = ps1[0][lane]+ps1[1][lane]+ps1[2][lane]+ps1[3][lane];
    pS2[(size_t)blockIdx.x*64 + lane] = ps2[0][lane]+ps2[1][lane]+ps2[2][lane]+ps2[3][lane];
  }
}

// ---------------------------------------------------------------------------
// K3b: slow path (expected ~0-5 rows): full f64 scan + 20x extraction.
// ---------------------------------------------------------------------------
__global__ __launch_bounds__(256) void k3b_slow(
    const float* __restrict__ xT, const double* __restrict__ xxd,
    const unsigned* __restrict__ slowcnt, const unsigned* __restrict__ slowlist,
    const float* __restrict__ uT, const float* __restrict__ vT,
    float* __restrict__ stage, double* __restrict__ k3bS1, double* __restrict__ k3bS2)
{
  __shared__ unsigned long long keyl[4096];
  __shared__ unsigned long long red[4];
  __shared__ unsigned t20[20];
  unsigned nslow = *slowcnt;
  int t = threadIdx.x;
  for (unsigned ii = blockIdx.x; ii < nslow; ii += gridDim.x) {
    int row = (int)slowlist[ii];
    int b = row >> 12, n = row & 4095;
    const float* pn = xT + ((size_t)b*4096 + n)*64;
    double xxn = xxd[(size_t)b*4096 + n];
    for (int m = t; m < 4096; m += 256) {
      const float* pm = xT + ((size_t)b*4096 + m)*64;
      double acc = 0.0;
      #pragma unroll 4
      for (int c = 0; c < 64; c += 4) {
        float4 a  = *(const float4*)(pn + c);
        float4 bf = *(const float4*)(pm + c);
        acc = fma((double)a.x, (double)bf.x, acc);
        acc = fma((double)a.y, (double)bf.y, acc);
        acc = fma((double)a.z, (double)bf.z, acc);
        acc = fma((double)a.w, (double)bf.w, acc);
      }
      double d = fmax(xxn + xxd[(size_t)b*4096 + m] - 2.0*acc, 0.0);
      keyl[m] = (((unsigned long long)__double_as_longlong(d)) & ~0xFFFull)
              | (unsigned long long)m;
    }
    __syncthreads();
    for (int k = 0; k < 20; ++k) {
      unsigned long long mn = ~0ull;
      #pragma unroll
      for (int s = 0; s < 16; ++s) {
        unsigned long long v = keyl[t + s*256];
        mn = (v < mn) ? v : mn;
      }
      for (int off = 32; off > 0; off >>= 1) {
        unsigned long long o = __shfl_down(mn, off);
        mn = (o < mn) ? o : mn;
      }
      if ((t & 63) == 0) red[t >> 6] = mn;
      __syncthreads();
      if (t == 0) {
        unsigned long long w0 = red[0];
        for (int q = 1; q < 4; ++q) w0 = (red[q] < w0) ? red[q] : w0;
        t20[k] = (unsigned)(w0 & 0xFFFull);
        keyl[w0 & 0xFFFull] = ~0ull;
      }
      __syncthreads();
    }
    if (t < 64) {
      const float* ub = uT + (size_t)b*4096*64;
      float mx = -3.4e38f, s1 = 0.f, s2 = 0.f;
      #pragma unroll
      for (int k = 0; k < 20; ++k) {
        unsigned m = t20[k];
        float g = ub[(size_t)m*64 + t];
        mx = fmaxf(mx, g); s1 += g; s2 = fmaf(g, g, s2);
      }
      size_t ro = ((size_t)b*4096 + n)*64 + t;
      float v = vT[ro];
      stage[ro] = mx + v;
      double dv = (double)v;
      __hip_atomic_fetch_add(&k3bS1[b*64 + t], (double)s1 + 20.0*dv,
                             __ATOMIC_RELAXED, __HIP_MEMORY_SCOPE_AGENT);
      __hip_atomic_fetch_add(&k3bS2[b*64 + t], (double)s2 + 2.0*dv*(double)s1 + 20.0*dv*dv,
                             __ATOMIC_RELAXED, __HIP_MEMORY_SCOPE_AGENT);
    }
    __syncthreads();
  }
}

// ---------------------------------------------------------------------------
// K4: reduce partials -> mean/var per (b,o); normalize + leaky-ReLU.
// ---------------------------------------------------------------------------
__global__ __launch_bounds__(256) void k4_final(
    const float* __restrict__ stage,
    const double* __restrict__ pS1, const double* __restrict__ pS2,
    const double* __restrict__ k3bS1, const double* __restrict__ k3bS2,
    float* __restrict__ out)
{
  __shared__ double r1[4], r2[4];
  __shared__ float params[2];
  int bo = blockIdx.x;
  int b = bo >> 6, o = bo & 63;
  int t = threadIdx.x;
  double s1 = 0.0, s2 = 0.0;
  for (int j = t; j < 1024; j += 256) {
    s1 += pS1[(size_t)(b*1024 + j)*64 + o];
    s2 += pS2[(size_t)(b*1024 + j)*64 + o];
  }
  for (int off = 32; off > 0; off >>= 1) {
    s1 += __shfl_down(s1, off);
    s2 += __shfl_down(s2, off);
  }
  if ((t & 63) == 0) { r1[t >> 6] = s1; r2[t >> 6] = s2; }
  __syncthreads();
  if (t == 0) {
    double S1 = r1[0]+r1[1]+r1[2]+r1[3] + k3bS1[bo];
    double S2 = r2[0]+r2[1]+r2[2]+r2[3] + k3bS2[bo];
    double inv = 1.0 / (4096.0 * 20.0);
    double mean = S1 * inv;
    double var  = S2 * inv - mean * mean;
    params[0] = (float)mean;
    params[1] = (float)rsqrt(var + 1e-5);
  }
  __syncthreads();
  float mf = params[0], rs = params[1];
  for (int n = t; n < 4096; n += 256) {
    float y = (stage[((size_t)b*4096 + n)*64 + o] - mf) * rs;
    out[(size_t)bo*4096 + n] = (y >= 0.f) ? y : 0.2f * y;
  }
}

// ---------------------------------------------------------------------------
extern "C" void kernel_launch(void* const* d_in, const int* in_sizes, int n_in,
                              void* d_out, int out_size, void* d_ws, size_t ws_size,
                              hipStream_t stream)
{
  (void)in_sizes; (void)n_in; (void)out_size; (void)ws_size;
  const float* x = (const float*)d_in[0];   // (4,64,4096)
  const float* W = (const float*)d_in[1];   // (64,128)
  float* out = (float*)d_out;

  char* ws = (char*)d_ws;
  size_t off = 0;
  auto alloc = [&](size_t bytes) {
    char* p = ws + off;
    off = (off + bytes + 255) & ~(size_t)255;
    return p;
  };
  float*          uT       = (float*)         alloc((size_t)NROW*64*4);
  float*          vT       = (float*)         alloc((size_t)NROW*64*4);
  float*          xT       = (float*)         alloc((size_t)NROW*64*4);
  float*          stage    = (float*)         alloc((size_t)NROW*64*4);
  unsigned short* xh       = (unsigned short*)alloc((size_t)NROW*64*2);
  float*          xxf      = (float*)         alloc((size_t)NROW*4);
  double*         xxd      = (double*)        alloc((size_t)NROW*8);
  double*         pS1      = (double*)        alloc((size_t)4096*64*8);
  double*         pS2      = (double*)        alloc((size_t)4096*64*8);
  unsigned*       counts   = (unsigned*)      alloc((size_t)NROW*NSEG*4);
  // zeroed region (contiguous): slowcnt, k3bS1, k3bS2
  unsigned*       slowcnt  = (unsigned*)      alloc(256);
  double*         k3bS1    = (double*)        alloc(256*8);
  double*         k3bS2    = (double*)        alloc(256*8);
  unsigned*       slowlist = (unsigned*)      alloc((size_t)NROW*4);
  unsigned*       surv     = (unsigned*)      alloc((size_t)NROW*SROW*4);

  hipMemsetAsync(slowcnt, 0, 256 + 2048 + 2048, stream);

  k1_prep  <<<256,  256, 0, stream>>>(x, W, xT, xh, xxf, xxd, uT, vT);
  k2_screen<<<512,  256, 0, stream>>>(xh, xxf, counts, surv);
  k3_select<<<4096, 256, 0, stream>>>(xT, xxd, counts, surv, uT, vT,
                                      stage, pS1, pS2, slowcnt, slowlist);
  k3b_slow <<<256,  256, 0, stream>>>(xT, xxd, slowcnt, slowlist,
                                      uT, vT, stage, k3bS1, k3bS2);
  k4_final <<<256,  256, 0, stream>>>(stage, pS1, pS2, k3bS1, k3bS2, out);
}

// Round 7
// 182.776 us; speedup vs baseline: 1.4340x; 1.0067x over previous
//
#include <hip/hip_runtime.h>
#include <hip/hip_bf16.h>
#include <cstdint>
#include <cstddef>

// Problem constants (fixed by reference)
#define BB 4
#define NN 4096
#define NROW (BB*NN)          // 16384 rows
#define SEGW 32               // slots per (row, m-split) segment
#define NSEG 16               // m-splits
#define SROW (SEGW*NSEG)      // 512 survivor slots per row
// fp16 screen: |w_approx - w_true| <= E = 0.29 (proven for ||x||^2<=140)
#define QPf 27.65f            // push threshold: STRICT(27) + 2E + slack
#define STRICT_Q 49152u       // q for w_approx < 27.0  ((27+69)*512)
#define DQ 300u               // window: ceil(2*E*512)+2

typedef float v2f   __attribute__((ext_vector_type(2)));
typedef float f32x16 __attribute__((ext_vector_type(16)));
typedef short s16x8 __attribute__((ext_vector_type(8)));
typedef _Float16 f16x8 __attribute__((ext_vector_type(8)));

__device__ __forceinline__ v2f pkfma(v2f a, v2f b, v2f c) {
  return __builtin_elementwise_fma(a, b, c);
}

// ---------------------------------------------------------------------------
// K1: prep. xT f32 [point][c]; xh fp16 [point][c]; xxf/xxd norms;
//     uT = W1.x, vT = (W2-W1).x  [point][o]  (weights in registers)
// ---------------------------------------------------------------------------
__global__ __launch_bounds__(256) void k1_prep(
    const float* __restrict__ x, const float* __restrict__ W,
    float* __restrict__ xT, unsigned short* __restrict__ xh,
    float* __restrict__ xxf, double* __restrict__ xxd,
    float* __restrict__ uT, float* __restrict__ vT)
{
  __shared__ float xc[64][65];   // [c][n]
  __shared__ float xr[64][68];   // [n][c]
  __shared__ float w1[64][65];
  __shared__ float wd[64][65];
  int t = threadIdx.x;
  int b  = blockIdx.x >> 6;
  int n0 = (blockIdx.x & 63) * 64;

  for (int i = t; i < 4096; i += 256) {
    int o = i >> 6, c = i & 63;
    float a = W[o*128 + c];
    w1[o][c] = a;
    wd[o][c] = W[o*128 + 64 + c] - a;
  }
  for (int i = t; i < 4096; i += 256) {
    int c = i >> 6, n = i & 63;
    xc[c][n] = x[((size_t)b*64 + c)*4096 + n0 + n];
  }
  __syncthreads();

  for (int i = t; i < 4096; i += 256) {
    int n = i >> 6, c = i & 63;
    float v = xc[c][n];
    xr[n][c] = v;
    size_t pi = ((size_t)b*4096 + n0 + n)*64 + c;
    xT[pi] = v;
    xh[pi] = __builtin_bit_cast(unsigned short, (_Float16)v);  // RNE cvt
  }
  if (t < 64) {
    int n = t;
    float s0=0,s1=0,s2=0,s3=0; double sd=0.0;
    for (int c = 0; c < 64; c += 4) {
      float a0=xc[c][n],a1=xc[c+1][n],a2=xc[c+2][n],a3=xc[c+3][n];
      s0=fmaf(a0,a0,s0); s1=fmaf(a1,a1,s1); s2=fmaf(a2,a2,s2); s3=fmaf(a3,a3,s3);
      sd += (double)a0*a0 + (double)a1*a1 + (double)a2*a2 + (double)a3*a3;
    }
    xxf[(size_t)b*4096 + n0 + n] = (s0+s1)+(s2+s3);
    xxd[(size_t)b*4096 + n0 + n] = sd;
  }
  v2f w1r[32], wdr[32];
  int o = t & 63;
  #pragma unroll
  for (int j = 0; j < 32; ++j) {
    w1r[j].x = w1[o][2*j]; w1r[j].y = w1[o][2*j+1];
    wdr[j].x = wd[o][2*j]; wdr[j].y = wd[o][2*j+1];
  }
  __syncthreads();

  for (int i = t; i < 4096; i += 256) {
    int n = i >> 6;
    v2f au; au.x=0.f; au.y=0.f;
    v2f av; av.x=0.f; av.y=0.f;
    #pragma unroll
    for (int cb = 0; cb < 16; ++cb) {
      float4 xv = *(const float4*)&xr[n][cb*4];
      v2f p0; p0.x = xv.x; p0.y = xv.y;
      v2f p1; p1.x = xv.z; p1.y = xv.w;
      au = pkfma(w1r[2*cb],   p0, au);
      au = pkfma(w1r[2*cb+1], p1, au);
      av = pkfma(wdr[2*cb],   p0, av);
      av = pkfma(wdr[2*cb+1], p1, av);
    }
    size_t idx = ((size_t)b*4096 + n0 + n)*64 + o;
    uT[idx] = au.x + au.y;
    vT[idx] = av.x + av.y;
  }
}

// ---------------------------------------------------------------------------
// K2: fp16 MFMA Gram screen, NO LDS staging (B-frags direct from global/L1,
// identical fragment layout as A), register double-buffered B. LDS = segcnt
// only. Grid = 64 n-blocks x 16 m-splits -> 1024 blocks (4 waves/SIMD).
// Block = 256 rows x 256 m, 8 mt-iters of 32 m.
// ---------------------------------------------------------------------------
__global__ __launch_bounds__(256) void k2_screen(
    const unsigned short* __restrict__ xh, const float* __restrict__ xxf,
    unsigned* __restrict__ counts, unsigned* __restrict__ surv)
{
  __shared__ unsigned segcnt[256];
  int t  = threadIdx.x;
  int nb = blockIdx.x >> 4;
  int ms = blockIdx.x & 15;
  int row0 = nb * 256;
  int b = row0 >> 12;
  int mbase = ms * 256;
  const unsigned short* xhB = xh + ((size_t)b*4096)*64;

  segcnt[t] = 0u;

  int wv = t >> 6, lane = t & 63;
  int lr = lane & 31, oct = lane >> 5;

  // A-fragments in registers (A,B fed with identical lane->element maps,
  // so any within-K ordering assumption cancels in the dot product)
  s16x8 ah[2][4];
  #pragma unroll
  for (int nt = 0; nt < 2; ++nt)
    #pragma unroll
    for (int ks = 0; ks < 4; ++ks)
      ah[nt][ks] = *(const s16x8*)(xh +
        ((size_t)(row0 + wv*64 + nt*32 + lr))*64 + ks*16 + oct*8);
  __syncthreads();

  // prime B double-buffer (mt = 0)
  s16x8 bh[4];
  #pragma unroll
  for (int ks = 0; ks < 4; ++ks)
    bh[ks] = *(const s16x8*)(xhB + (size_t)(mbase + lr)*64 + ks*16 + oct*8);

  for (int mt = 0; mt < 8; ++mt) {
    int m0 = mbase + mt*32;
    float xxm = xxf[b*4096 + m0 + lr];        // issued early, used in epilogue
    s16x8 bhn[4];
    if (mt < 7) {
      #pragma unroll
      for (int ks = 0; ks < 4; ++ks)
        bhn[ks] = *(const s16x8*)(xhB + (size_t)(m0 + 32 + lr)*64 + ks*16 + oct*8);
    }

    f32x16 a0, a1;
    #pragma unroll
    for (int i = 0; i < 16; ++i) { a0[i] = 0.f; a1[i] = 0.f; }
    #pragma unroll
    for (int ks = 0; ks < 4; ++ks) {
      f16x8 AH0 = __builtin_bit_cast(f16x8, ah[0][ks]);
      f16x8 AH1 = __builtin_bit_cast(f16x8, ah[1][ks]);
      f16x8 BH  = __builtin_bit_cast(f16x8, bh[ks]);
      a0 = __builtin_amdgcn_mfma_f32_32x32x16_f16(AH0, BH, a0, 0, 0, 0);
      a1 = __builtin_amdgcn_mfma_f32_32x32x16_f16(AH1, BH, a1, 0, 0, 0);
    }

    // epilogue: w = xx_m - 2*S ; LDS-atomic slot, fire-and-forget store
    int mg = m0 + lr;
    #pragma unroll
    for (int i = 0; i < 16; ++i) {
      const int base_i = (i & 3) + 8*(i >> 2);   // C/D row map (measured)
      {
        float w = fmaf(-2.0f, a0[i], xxm);
        if (w < QPf) {
          int rloc = wv*64 + base_i + 4*oct;
          int qi = (int)((w + 69.0f) * 512.0f);
          qi = min(max(qi, 0), 65535);
          unsigned key = ((unsigned)qi << 12) | (unsigned)mg;
          unsigned slot = atomicAdd(&segcnt[rloc], 1u);
          if (slot < SEGW) surv[(size_t)(row0 + rloc)*SROW + ms*SEGW + slot] = key;
        }
      }
      {
        float w = fmaf(-2.0f, a1[i], xxm);
        if (w < QPf) {
          int rloc = wv*64 + 32 + base_i + 4*oct;
          int qi = (int)((w + 69.0f) * 512.0f);
          qi = min(max(qi, 0), 65535);
          unsigned key = ((unsigned)qi << 12) | (unsigned)mg;
          unsigned slot = atomicAdd(&segcnt[rloc], 1u);
          if (slot < SEGW) surv[(size_t)(row0 + rloc)*SROW + ms*SEGW + slot] = key;
        }
      }
    }
    #pragma unroll
    for (int ks = 0; ks < 4; ++ks) bh[ks] = bhn[ks];
  }
  __syncthreads();
  counts[(size_t)(row0 + t)*NSEG + ms] = segcnt[t];   // unique writer
}

// ---------------------------------------------------------------------------
// K3: per-row wave. 16 segments x 32 slots -> key[8] (segment pair per
// lane-half); strict check; 16-iter q-bisection; window select (superset of
// true top-20); f64 rescore; bitonic sort; gather/max epilogue.
// ---------------------------------------------------------------------------
__global__ __launch_bounds__(256) void k3_select(
    const float* __restrict__ xT, const double* __restrict__ xxd,
    const unsigned* __restrict__ counts, const unsigned* __restrict__ surv,
    const float* __restrict__ uT, const float* __restrict__ vT,
    float* __restrict__ stage, double* __restrict__ pS1, double* __restrict__ pS2,
    unsigned* __restrict__ slowcnt, unsigned* __restrict__ slowlist)
{
  __shared__ unsigned candm[4][64];
  __shared__ double ps1[4][64], ps2[4][64];
  int wv = threadIdx.x >> 6, lane = threadIdx.x & 63;
  int row = blockIdx.x * 4 + wv;
  int b = row >> 12, n = row & 4095;

  double s1t = 0.0, s2t = 0.0;

  uint4 c0 = *(const uint4*)&counts[(size_t)row*NSEG];
  uint4 c1 = *(const uint4*)&counts[(size_t)row*NSEG + 4];
  uint4 c2 = *(const uint4*)&counts[(size_t)row*NSEG + 8];
  uint4 c3 = *(const uint4*)&counts[(size_t)row*NSEG + 12];
  bool slow = (c0.x > SEGW) | (c0.y > SEGW) | (c0.z > SEGW) | (c0.w > SEGW)
            | (c1.x > SEGW) | (c1.y > SEGW) | (c1.z > SEGW) | (c1.w > SEGW)
            | (c2.x > SEGW) | (c2.y > SEGW) | (c2.z > SEGW) | (c2.w > SEGW)
            | (c3.x > SEGW) | (c3.y > SEGW) | (c3.z > SEGW) | (c3.w > SEGW);

  int half = lane >> 5, idx = lane & 31;
  unsigned sc[8];
  sc[0] = half ? c0.y : c0.x;
  sc[1] = half ? c0.w : c0.z;
  sc[2] = half ? c1.y : c1.x;
  sc[3] = half ? c1.w : c1.z;
  sc[4] = half ? c2.y : c2.x;
  sc[5] = half ? c2.w : c2.z;
  sc[6] = half ? c3.y : c3.x;
  sc[7] = half ? c3.w : c3.z;

  unsigned key[8];
  #pragma unroll
  for (int s = 0; s < 8; ++s) {
    int sg = 2*s + half;
    key[s] = (!slow && idx < (int)sc[s])
           ? surv[(size_t)row*SROW + sg*SEGW + idx] : 0xFFFFFFFFu;
  }

  int strictc = 0;
  #pragma unroll
  for (int s = 0; s < 8; ++s)
    strictc += __popcll(__ballot(key[s] < (STRICT_Q << 12)));
  slow = slow || (strictc < 20);

  int sel = 0;
  if (!slow) {
    // bisect on 16-bit q field: find q20 (q of 20th-smallest key)
    unsigned lo = 0u, hi = 1u << 16;
    for (int it = 0; it < 16; ++it) {
      unsigned mid = (lo + hi) >> 1;
      unsigned Tm = mid << 12;
      int c = 0;
      #pragma unroll
      for (int s = 0; s < 8; ++s)
        c += __popcll(__ballot(key[s] < Tm));
      if (c >= 20) hi = mid; else lo = mid;
    }
    unsigned T = (lo + DQ) << 12;    // window covers q20 .. q20+DQ-1
    int c = 0;
    #pragma unroll
    for (int s = 0; s < 8; ++s)
      c += __popcll(__ballot(key[s] < T));
    sel = c;
    if (sel > 64) {
      slow = true;
    } else {
      int base = 0;
      #pragma unroll
      for (int s = 0; s < 8; ++s) {
        unsigned long long mask = __ballot(key[s] < T);
        if (key[s] < T) {
          int pos = base + __popcll(mask & ((1ull << lane) - 1ull));
          candm[wv][pos] = key[s] & 0xFFFu;
        }
        base += __popcll(mask);
      }
    }
  }

  if (!slow) {
    __builtin_amdgcn_wave_barrier();
    unsigned long long k64 = ~0ull;
    if (lane < sel) {
      int m = (int)candm[wv][lane];
      const float* pn = xT + ((size_t)b*4096 + n)*64;
      const float* pm = xT + ((size_t)b*4096 + m)*64;
      double acc = 0.0;
      #pragma unroll 4
      for (int c5 = 0; c5 < 64; c5 += 4) {
        float4 a  = *(const float4*)(pn + c5);
        float4 bf = *(const float4*)(pm + c5);
        acc = fma((double)a.x, (double)bf.x, acc);
        acc = fma((double)a.y, (double)bf.y, acc);
        acc = fma((double)a.z, (double)bf.z, acc);
        acc = fma((double)a.w, (double)bf.w, acc);
      }
      double d = xxd[(size_t)b*4096 + n] + xxd[(size_t)b*4096 + m] - 2.0*acc;
      d = fmax(d, 0.0);
      k64 = (((unsigned long long)__double_as_longlong(d)) & ~0xFFFull)
          | (unsigned long long)m;            // tie -> lower index (lax.top_k)
    }
    #pragma unroll
    for (int kk = 2; kk <= 64; kk <<= 1) {
      #pragma unroll
      for (int j = kk >> 1; j > 0; j >>= 1) {
        unsigned long long o = __shfl_xor(k64, j);
        bool up    = ((lane & kk) == 0);
        bool lower = ((lane & j) == 0);
        unsigned long long mn = (k64 < o) ? k64 : o;
        unsigned long long mx = (k64 < o) ? o : k64;
        k64 = (lower == up) ? mn : mx;
      }
    }
    int mlow = (int)(k64 & 0xFFFull);          // lanes 0..19 = top-20
    const float* ub = uT + (size_t)b*4096*64;
    float mx = -3.4e38f, s1 = 0.f, s2 = 0.f;
    #pragma unroll
    for (int k = 0; k < 20; ++k) {
      int m = __shfl(mlow, k);
      float g = ub[(size_t)m*64 + lane];
      mx = fmaxf(mx, g); s1 += g; s2 = fmaf(g, g, s2);
    }
    size_t ro = ((size_t)b*4096 + n)*64 + lane;
    float v = vT[ro];
    stage[ro] = mx + v;
    double dv = (double)v;
    s1t = (double)s1 + 20.0*dv;
    s2t = (double)s2 + 2.0*dv*(double)s1 + 20.0*dv*dv;
  } else {
    if (lane == 0) { unsigned i = atomicAdd(slowcnt, 1u); slowlist[i] = row; }
  }

  ps1[wv][lane] = s1t; ps2[wv][lane] = s2t;
  __syncthreads();
  if (wv == 0) {
    pS1[(size_t)blockIdx.x*64 + lane] = ps1[0][lane]+ps1[1][lane]+ps1[2][lane]+ps1[3][lane];
    pS2[(size_t)blockIdx.x*64 + lane] = ps2[0][lane]+ps2[1][lane]+ps2[2][lane]+ps2[3][lane];
  }
}

// ---------------------------------------------------------------------------
// K3b: slow path (expected ~0-10 rows): full f64 scan + 20x extraction.
// ---------------------------------------------------------------------------
__global__ __launch_bounds__(256) void k3b_slow(
    const float* __restrict__ xT, const double* __restrict__ xxd,
    const unsigned* __restrict__ slowcnt, const unsigned* __restrict__ slowlist,
    const float* __restrict__ uT, const float* __restrict__ vT,
    float* __restrict__ stage, double* __restrict__ k3bS1, double* __restrict__ k3bS2)
{
  __shared__ unsigned long long keyl[4096];
  __shared__ unsigned long long red[4];
  __shared__ unsigned t20[20];
  unsigned nslow = *slowcnt;
  int t = threadIdx.x;
  for (unsigned ii = blockIdx.x; ii < nslow; ii += gridDim.x) {
    int row = (int)slowlist[ii];
    int b = row >> 12, n = row & 4095;
    const float* pn = xT + ((size_t)b*4096 + n)*64;
    double xxn = xxd[(size_t)b*4096 + n];
    for (int m = t; m < 4096; m += 256) {
      const float* pm = xT + ((size_t)b*4096 + m)*64;
      double acc = 0.0;
      #pragma unroll 4
      for (int c = 0; c < 64; c += 4) {
        float4 a  = *(const float4*)(pn + c);
        float4 bf = *(const float4*)(pm + c);
        acc = fma((double)a.x, (double)bf.x, acc);
        acc = fma((double)a.y, (double)bf.y, acc);
        acc = fma((double)a.z, (double)bf.z, acc);
        acc = fma((double)a.w, (double)bf.w, acc);
      }
      double d = fmax(xxn + xxd[(size_t)b*4096 + m] - 2.0*acc, 0.0);
      keyl[m] = (((unsigned long long)__double_as_longlong(d)) & ~0xFFFull)
              | (unsigned long long)m;
    }
    __syncthreads();
    for (int k = 0; k < 20; ++k) {
      unsigned long long mn = ~0ull;
      #pragma unroll
      for (int s = 0; s < 16; ++s) {
        unsigned long long v = keyl[t + s*256];
        mn = (v < mn) ? v : mn;
      }
      for (int off = 32; off > 0; off >>= 1) {
        unsigned long long o = __shfl_down(mn, off);
        mn = (o < mn) ? o : mn;
      }
      if ((t & 63) == 0) red[t >> 6] = mn;
      __syncthreads();
      if (t == 0) {
        unsigned long long w0 = red[0];
        for (int q = 1; q < 4; ++q) w0 = (red[q] < w0) ? red[q] : w0;
        t20[k] = (unsigned)(w0 & 0xFFFull);
        keyl[w0 & 0xFFFull] = ~0ull;
      }
      __syncthreads();
    }
    if (t < 64) {
      const float* ub = uT + (size_t)b*4096*64;
      float mx = -3.4e38f, s1 = 0.f, s2 = 0.f;
      #pragma unroll
      for (int k = 0; k < 20; ++k) {
        unsigned m = t20[k];
        float g = ub[(size_t)m*64 + t];
        mx = fmaxf(mx, g); s1 += g; s2 = fmaf(g, g, s2);
      }
      size_t ro = ((size_t)b*4096 + n)*64 + t;
      float v = vT[ro];
      stage[ro] = mx + v;
      double dv = (double)v;
      __hip_atomic_fetch_add(&k3bS1[b*64 + t], (double)s1 + 20.0*dv,
                             __ATOMIC_RELAXED, __HIP_MEMORY_SCOPE_AGENT);
      __hip_atomic_fetch_add(&k3bS2[b*64 + t], (double)s2 + 2.0*dv*(double)s1 + 20.0*dv*dv,
                             __ATOMIC_RELAXED, __HIP_MEMORY_SCOPE_AGENT);
    }
    __syncthreads();
  }
}

// ---------------------------------------------------------------------------
// K4: reduce partials -> mean/var per (b,o); normalize + leaky-ReLU.
// ---------------------------------------------------------------------------
__global__ __launch_bounds__(256) void k4_final(
    const float* __restrict__ stage,
    const double* __restrict__ pS1, const double* __restrict__ pS2,
    const double* __restrict__ k3bS1, const double* __restrict__ k3bS2,
    float* __restrict__ out)
{
  __shared__ double r1[4], r2[4];
  __shared__ float params[2];
  int bo = blockIdx.x;
  int b = bo >> 6, o = bo & 63;
  int t = threadIdx.x;
  double s1 = 0.0, s2 = 0.0;
  for (int j = t; j < 1024; j += 256) {
    s1 += pS1[(size_t)(b*1024 + j)*64 + o];
    s2 += pS2[(size_t)(b*1024 + j)*64 + o];
  }
  for (int off = 32; off > 0; off >>= 1) {
    s1 += __shfl_down(s1, off);
    s2 += __shfl_down(s2, off);
  }
  if ((t & 63) == 0) { r1[t >> 6] = s1; r2[t >> 6] = s2; }
  __syncthreads();
  if (t == 0) {
    double S1 = r1[0]+r1[1]+r1[2]+r1[3] + k3bS1[bo];
    double S2 = r2[0]+r2[1]+r2[2]+r2[3] + k3bS2[bo];
    double inv = 1.0 / (4096.0 * 20.0);
    double mean = S1 * inv;
    double var  = S2 * inv - mean * mean;
    params[0] = (float)mean;
    params[1] = (float)rsqrt(var + 1e-5);
  }
  __syncthreads();
  float mf = params[0], rs = params[1];
  for (int n = t; n < 4096; n += 256) {
    float y = (stage[((size_t)b*4096 + n)*64 + o] - mf) * rs;
    out[(size_t)bo*4096 + n] = (y >= 0.f) ? y : 0.2f * y;
  }
}

// ---------------------------------------------------------------------------
extern "C" void kernel_launch(void* const* d_in, const int* in_sizes, int n_in,
                              void* d_out, int out_size, void* d_ws, size_t ws_size,
                              hipStream_t stream)
{
  (void)in_sizes; (void)n_in; (void)out_size; (void)ws_size;
  const float* x = (const float*)d_in[0];   // (4,64,4096)
  const float* W = (const float*)d_in[1];   // (64,128)
  float* out = (float*)d_out;

  char* ws = (char*)d_ws;
  size_t off = 0;
  auto alloc = [&](size_t bytes) {
    char* p = ws + off;
    off = (off + bytes + 255) & ~(size_t)255;
    return p;
  };
  float*          uT       = (float*)         alloc((size_t)NROW*64*4);
  float*          vT       = (float*)         alloc((size_t)NROW*64*4);
  float*          xT       = (float*)         alloc((size_t)NROW*64*4);
  float*          stage    = (float*)         alloc((size_t)NROW*64*4);
  unsigned short* xh       = (unsigned short*)alloc((size_t)NROW*64*2);
  float*          xxf      = (float*)         alloc((size_t)NROW*4);
  double*         xxd      = (double*)        alloc((size_t)NROW*8);
  double*         pS1      = (double*)        alloc((size_t)4096*64*8);
  double*         pS2      = (double*)        alloc((size_t)4096*64*8);
  unsigned*       counts   = (unsigned*)      alloc((size_t)NROW*NSEG*4);
  // zeroed region (contiguous): slowcnt, k3bS1, k3bS2
  unsigned*       slowcnt  = (unsigned*)      alloc(256);
  double*         k3bS1    = (double*)        alloc(256*8);
  double*         k3bS2    = (double*)        alloc(256*8);
  unsigned*       slowlist = (unsigned*)      alloc((size_t)NROW*4);
  unsigned*       surv     = (unsigned*)      alloc((size_t)NROW*SROW*4);

  hipMemsetAsync(slowcnt, 0, 256 + 2048 + 2048, stream);

  k1_prep  <<<256,  256, 0, stream>>>(x, W, xT, xh, xxf, xxd, uT, vT);
  k2_screen<<<1024, 256, 0, stream>>>(xh, xxf, counts, surv);
  k3_select<<<4096, 256, 0, stream>>>(xT, xxd, counts, surv, uT, vT,
                                      stage, pS1, pS2, slowcnt, slowlist);
  k3b_slow <<<256,  256, 0, stream>>>(xT, xxd, slowcnt, slowlist,
                                      uT, vT, stage, k3bS1, k3bS2);
  k4_final <<<256,  256, 0, stream>>>(stage, pS1, pS2, k3bS1, k3bS2, out);
}